// Round 2
// baseline (146.620 us; speedup 1.0000x reference)
//
#include <hip/hip_runtime.h>
#include <math.h>

#define NN 8192
#define FF 128
#define CAP 128

// --- per-row attention dots: f1[i] = x[i]·a[0:128], f2[i] = x[i]·a[128:256]
__global__ __launch_bounds__(256) void k_scores(const float* __restrict__ x,
                                                const float* __restrict__ a,
                                                float* __restrict__ f1,
                                                float* __restrict__ f2) {
  int gid = blockIdx.x * blockDim.x + threadIdx.x;
  int row = gid >> 6;
  int lane = gid & 63;
  if (row >= NN) return;
  const float* xr = x + (size_t)row * FF;
  float v0 = xr[lane], v1 = xr[lane + 64];
  float s1 = v0 * a[lane] + v1 * a[lane + 64];
  float s2 = v0 * a[FF + lane] + v1 * a[FF + lane + 64];
  #pragma unroll
  for (int off = 32; off > 0; off >>= 1) {
    s1 += __shfl_down(s1, off);
    s2 += __shfl_down(s2, off);
  }
  if (lane == 0) { f1[row] = s1; f2[row] = s2; }
}

// --- one block per row: stream adj row (barrier-free ballot compaction),
//     single-wave softmax, U@x, forward lifting
__global__ __launch_bounds__(256) void k_build(
    const float* __restrict__ adj, const float* __restrict__ x,
    const float* __restrict__ f1g, const float* __restrict__ f2g,
    const float* __restrict__ temp,
    int* __restrict__ nnzg, int* __restrict__ colsg, float* __restrict__ valsg,
    float* __restrict__ rowsumg, float* __restrict__ featg) {
  const int row = blockIdx.x;
  const int t = threadIdx.x;
  const int lane = t & 63, w = t >> 6;

  __shared__ int   s_cols[CAP];
  __shared__ float s_u[CAP];
  __shared__ int   s_cnt[32];     // per (iteration, wave) nonzero count
  __shared__ float s_rs;          // broadcast rowsum
  __shared__ float s_part[256];

  // ---- barrier-free deterministic compaction ----
  const float4* arow = (const float4*)(adj + (size_t)row * NN);
  unsigned msk[8];
  int within[8];
  const unsigned long long lt = (1ull << lane) - 1ull;
  #pragma unroll
  for (int it = 0; it < 8; ++it) {
    float4 v = arow[it * 256 + t];
    bool c0 = v.x > 0.f, c1 = v.y > 0.f, c2 = v.z > 0.f, c3 = v.w > 0.f;
    unsigned long long b0 = __ballot(c0), b1 = __ballot(c1),
                       b2 = __ballot(c2), b3 = __ballot(c3);
    within[it] = __popcll(b0 & lt) + __popcll(b1 & lt) +
                 __popcll(b2 & lt) + __popcll(b3 & lt);
    msk[it] = (c0 ? 1u : 0u) | (c1 ? 2u : 0u) | (c2 ? 4u : 0u) | (c3 ? 8u : 0u);
    if (lane == 0)
      s_cnt[it * 4 + w] = __popcll(b0) + __popcll(b1) + __popcll(b2) + __popcll(b3);
  }
  __syncthreads();

  int base[8];
  int run = 0;
  #pragma unroll
  for (int it = 0; it < 8; ++it) {
    #pragma unroll
    for (int ww = 0; ww < 4; ++ww) {
      if (ww == w) base[it] = run;
      run += s_cnt[it * 4 + ww];
    }
  }
  const int cnt = run < CAP ? run : CAP;   // uniform across block

  #pragma unroll
  for (int it = 0; it < 8; ++it) {
    unsigned m = msk[it];
    if (m) {
      int pos = base[it] + within[it];
      int j0 = (it * 256 + t) * 4;
      if (m & 1u) { if (pos < CAP) s_cols[pos] = j0;     pos++; }
      if (m & 2u) { if (pos < CAP) s_cols[pos] = j0 + 1; pos++; }
      if (m & 4u) { if (pos < CAP) s_cols[pos] = j0 + 2; pos++; }
      if (m & 8u) { if (pos < CAP) s_cols[pos] = j0 + 3; pos++; }
    }
  }
  __syncthreads();

  // ---- single-wave softmax + rowsum + persist sparse row ----
  if (w == 0) {
    float F1 = f1g[row];
    int i0 = lane, i1 = lane + 64;
    int col0 = (i0 < cnt) ? s_cols[i0] : 0;
    int col1 = (i1 < cnt) ? s_cols[i1] : 0;
    float e0 = -INFINITY, e1 = -INFINITY;
    if (i0 < cnt) { float s = F1 + f2g[col0]; e0 = s > 0.f ? s : 0.2f * s; }
    if (i1 < cnt) { float s = F1 + f2g[col1]; e1 = s > 0.f ? s : 0.2f * s; }
    float mx = fmaxf(e0, e1);
    #pragma unroll
    for (int off = 32; off > 0; off >>= 1) mx = fmaxf(mx, __shfl_xor(mx, off));
    float p0 = (i0 < cnt) ? expf(e0 - mx) : 0.f;
    float p1 = (i1 < cnt) ? expf(e1 - mx) : 0.f;
    float sm = p0 + p1;
    #pragma unroll
    for (int off = 32; off > 0; off >>= 1) sm += __shfl_xor(sm, off);
    float inv = 1.f / sm;
    float u0 = p0 * inv, u1 = p1 * inv;
    if (i0 < cnt) s_u[i0] = u0;
    if (i1 < cnt) s_u[i1] = u1;
    float q = u0 * u0 + u1 * u1;
    #pragma unroll
    for (int off = 32; off > 0; off >>= 1) q += __shfl_xor(q, off);
    float rs = 0.5f * q;
    if (lane == 0) { s_rs = rs; rowsumg[row] = rs; nnzg[row] = cnt; }
    int* cg = colsg + (size_t)row * CAP;
    float* vg = valsg + (size_t)row * CAP;
    if (i0 < cnt) { cg[i0] = col0; vg[i0] = u0; }
    if (i1 < cnt) { cg[i1] = col1; vg[i1] = u1; }
  }
  __syncthreads();
  float rsum = s_rs;

  // ---- prop_u = U @ x ; feat = prop_u - x*rowsum + (1-coe2)*x ----
  float coe2 = 1.f / (1.f + expf(-temp[2]));
  int f = t & 127, half = t >> 7;
  float acc = 0.f;
  for (int k = half; k < cnt; k += 2)
    acc += s_u[k] * x[(size_t)s_cols[k] * FF + f];
  s_part[t] = acc;
  __syncthreads();
  if (t < FF) {
    float prop = s_part[t] + s_part[t + FF];
    float xv = x[(size_t)row * FF + t];
    featg[(size_t)row * FF + t] = prop - xv * rsum + (1.f - coe2) * xv;
  }
}

// --- second SpMM + inverse lifting + output blend
__global__ __launch_bounds__(256) void k_apply(
    const float* __restrict__ featg, const float* __restrict__ h0,
    const float* __restrict__ temp,
    const int* __restrict__ nnzg, const int* __restrict__ colsg,
    const float* __restrict__ valsg, const float* __restrict__ rowsumg,
    float* __restrict__ out) {
  const int row = blockIdx.x;
  const int t = threadIdx.x;
  __shared__ int   s_cols[CAP];
  __shared__ float s_u[CAP];
  __shared__ float s_part[256];
  int cnt = nnzg[row];
  const int* cg = colsg + (size_t)row * CAP;
  const float* vg = valsg + (size_t)row * CAP;
  if (t < cnt) { s_cols[t] = cg[t]; s_u[t] = vg[t]; }
  __syncthreads();
  int f = t & 127, half = t >> 7;
  float acc = 0.f;
  for (int k = half; k < cnt; k += 2)
    acc += s_u[k] * featg[(size_t)s_cols[k] * FF + f];
  s_part[t] = acc;
  __syncthreads();
  if (t < FF) {
    float prop2 = s_part[t] + s_part[t + FF];
    float ft = featg[(size_t)row * FF + t];
    float rs = rowsumg[row];
    float coe1 = 1.f / (1.f + expf(-temp[1]));
    float coe3 = 1.f / (1.f + expf(-temp[3]));
    float odd = ft - prop2;
    float even = coe3 * prop2 + odd * rs;
    float fp = coe1 * even + (1.f - coe1) * odd;
    out[(size_t)row * FF + t] = 0.2f * fp + 0.8f * h0[(size_t)row * FF + t];
  }
}

extern "C" void kernel_launch(void* const* d_in, const int* in_sizes, int n_in,
                              void* d_out, int out_size, void* d_ws, size_t ws_size,
                              hipStream_t stream) {
  const float* x    = (const float*)d_in[0];
  const float* h0   = (const float*)d_in[1];
  const float* adj  = (const float*)d_in[2];
  const float* a    = (const float*)d_in[3];
  const float* temp = (const float*)d_in[4];
  float* out = (float*)d_out;

  float* f1 = (float*)d_ws;
  float* f2 = f1 + NN;
  float* rowsum = f2 + NN;
  int*   nnz = (int*)(rowsum + NN);
  int*   cols = nnz + NN;
  float* vals = (float*)(cols + (size_t)NN * CAP);
  float* feat = vals + (size_t)NN * CAP;

  k_scores<<<NN / 4, 256, 0, stream>>>(x, a, f1, f2);
  k_build<<<NN, 256, 0, stream>>>(adj, x, f1, f2, temp, nnz, cols, vals, rowsum, feat);
  k_apply<<<NN, 256, 0, stream>>>(feat, h0, temp, nnz, cols, vals, rowsum, out);
}

// Round 4
// 103.730 us; speedup vs baseline: 1.4135x; 1.4135x over previous
//
#include <hip/hip_runtime.h>
#include <math.h>

#define NN 8192
#define FF 128
#define CAP 128

typedef float nfloat4 __attribute__((ext_vector_type(4)));

// --- per-row attention dots: f1[i] = x[i]·a[0:128], f2[i] = x[i]·a[128:256]
__global__ __launch_bounds__(256) void k_scores(const float* __restrict__ x,
                                                const float* __restrict__ a,
                                                float* __restrict__ f1,
                                                float* __restrict__ f2) {
  int gid = blockIdx.x * blockDim.x + threadIdx.x;
  int row = gid >> 6;
  int lane = gid & 63;
  if (row >= NN) return;
  const float* xr = x + (size_t)row * FF;
  float v0 = xr[lane], v1 = xr[lane + 64];
  float s1 = v0 * a[lane] + v1 * a[lane + 64];
  float s2 = v0 * a[FF + lane] + v1 * a[FF + lane + 64];
  #pragma unroll
  for (int off = 32; off > 0; off >>= 1) {
    s1 += __shfl_down(s1, off);
    s2 += __shfl_down(s2, off);
  }
  if (lane == 0) { f1[row] = s1; f2[row] = s2; }
}

// --- one block per row: nontemporal adj stream, ballot compaction,
//     single-wave softmax, unrolled U@x gather, forward lifting
__global__ __launch_bounds__(256) void k_build(
    const float* __restrict__ adj, const float* __restrict__ x,
    const float* __restrict__ f1g, const float* __restrict__ f2g,
    const float* __restrict__ temp,
    int* __restrict__ nnzg, int* __restrict__ colsg, float* __restrict__ valsg,
    float* __restrict__ rowsumg, float* __restrict__ featg) {
  const int row = blockIdx.x;
  const int t = threadIdx.x;
  const int lane = t & 63, w = t >> 6;

  __shared__ int   s_cols[CAP];
  __shared__ float s_u[CAP];
  __shared__ int   s_cnt[32];
  __shared__ float s_rs;
  __shared__ float s_part[256];

  // ---- barrier-free deterministic compaction (nontemporal adj stream) ----
  const nfloat4* arow = (const nfloat4*)(adj + (size_t)row * NN);
  unsigned msk[8];
  int within[8];
  const unsigned long long lt = (1ull << lane) - 1ull;
  #pragma unroll
  for (int it = 0; it < 8; ++it) {
    nfloat4 v = __builtin_nontemporal_load(&arow[it * 256 + t]);
    bool c0 = v.x > 0.f, c1 = v.y > 0.f, c2 = v.z > 0.f, c3 = v.w > 0.f;
    unsigned long long b0 = __ballot(c0), b1 = __ballot(c1),
                       b2 = __ballot(c2), b3 = __ballot(c3);
    within[it] = __popcll(b0 & lt) + __popcll(b1 & lt) +
                 __popcll(b2 & lt) + __popcll(b3 & lt);
    msk[it] = (c0 ? 1u : 0u) | (c1 ? 2u : 0u) | (c2 ? 4u : 0u) | (c3 ? 8u : 0u);
    if (lane == 0)
      s_cnt[it * 4 + w] = __popcll(b0) + __popcll(b1) + __popcll(b2) + __popcll(b3);
  }
  __syncthreads();

  int base[8];
  int run = 0;
  #pragma unroll
  for (int it = 0; it < 8; ++it) {
    #pragma unroll
    for (int ww = 0; ww < 4; ++ww) {
      if (ww == w) base[it] = run;
      run += s_cnt[it * 4 + ww];
    }
  }
  const int cnt = run < CAP ? run : CAP;

  #pragma unroll
  for (int it = 0; it < 8; ++it) {
    unsigned m = msk[it];
    if (m) {
      int pos = base[it] + within[it];
      int j0 = (it * 256 + t) * 4;
      if (m & 1u) { if (pos < CAP) s_cols[pos] = j0;     pos++; }
      if (m & 2u) { if (pos < CAP) s_cols[pos] = j0 + 1; pos++; }
      if (m & 4u) { if (pos < CAP) s_cols[pos] = j0 + 2; pos++; }
      if (m & 8u) { if (pos < CAP) s_cols[pos] = j0 + 3; pos++; }
    }
  }
  __syncthreads();

  // ---- single-wave softmax + rowsum + persist sparse row ----
  if (w == 0) {
    float F1 = f1g[row];
    int i0 = lane, i1 = lane + 64;
    int col0 = (i0 < cnt) ? s_cols[i0] : 0;
    int col1 = (i1 < cnt) ? s_cols[i1] : 0;
    float e0 = -INFINITY, e1 = -INFINITY;
    if (i0 < cnt) { float s = F1 + f2g[col0]; e0 = s > 0.f ? s : 0.2f * s; }
    if (i1 < cnt) { float s = F1 + f2g[col1]; e1 = s > 0.f ? s : 0.2f * s; }
    float mx = fmaxf(e0, e1);
    #pragma unroll
    for (int off = 32; off > 0; off >>= 1) mx = fmaxf(mx, __shfl_xor(mx, off));
    float p0 = (i0 < cnt) ? expf(e0 - mx) : 0.f;
    float p1 = (i1 < cnt) ? expf(e1 - mx) : 0.f;
    float sm = p0 + p1;
    #pragma unroll
    for (int off = 32; off > 0; off >>= 1) sm += __shfl_xor(sm, off);
    float inv = 1.f / sm;
    float u0 = p0 * inv, u1 = p1 * inv;
    if (i0 < cnt) s_u[i0] = u0;
    if (i1 < cnt) s_u[i1] = u1;
    float q = u0 * u0 + u1 * u1;
    #pragma unroll
    for (int off = 32; off > 0; off >>= 1) q += __shfl_xor(q, off);
    float rs = 0.5f * q;
    if (lane == 0) { s_rs = rs; rowsumg[row] = rs; nnzg[row] = cnt; }
    int* cg = colsg + (size_t)row * CAP;
    float* vg = valsg + (size_t)row * CAP;
    if (i0 < cnt) { cg[i0] = col0; vg[i0] = u0; }
    if (i1 < cnt) { cg[i1] = col1; vg[i1] = u1; }
  }
  __syncthreads();
  float rsum = s_rs;

  // ---- prop_u = U @ x : 4 independent gathers in flight per round ----
  float coe2 = 1.f / (1.f + expf(-temp[2]));
  int f = t & 127, half = t >> 7;
  float acc = 0.f;
  int k = half;
  for (; k + 6 < cnt; k += 8) {
    int   c0 = s_cols[k],     c1 = s_cols[k + 2], c2 = s_cols[k + 4], c3 = s_cols[k + 6];
    float u0 = s_u[k],        u1 = s_u[k + 2],    u2 = s_u[k + 4],    u3 = s_u[k + 6];
    float v0 = x[(size_t)c0 * FF + f];
    float v1 = x[(size_t)c1 * FF + f];
    float v2 = x[(size_t)c2 * FF + f];
    float v3 = x[(size_t)c3 * FF + f];
    acc += u0 * v0 + u1 * v1 + u2 * v2 + u3 * v3;
  }
  for (; k < cnt; k += 2)
    acc += s_u[k] * x[(size_t)s_cols[k] * FF + f];
  s_part[t] = acc;
  __syncthreads();
  if (t < FF) {
    float prop = s_part[t] + s_part[t + FF];
    float xv = x[(size_t)row * FF + t];
    featg[(size_t)row * FF + t] = prop - xv * rsum + (1.f - coe2) * xv;
  }
}

// --- second SpMM (unrolled gathers) + inverse lifting + output blend
__global__ __launch_bounds__(256) void k_apply(
    const float* __restrict__ featg, const float* __restrict__ h0,
    const float* __restrict__ temp,
    const int* __restrict__ nnzg, const int* __restrict__ colsg,
    const float* __restrict__ valsg, const float* __restrict__ rowsumg,
    float* __restrict__ out) {
  const int row = blockIdx.x;
  const int t = threadIdx.x;
  __shared__ int   s_cols[CAP];
  __shared__ float s_u[CAP];
  __shared__ float s_part[256];
  int cnt = nnzg[row];
  const int* cg = colsg + (size_t)row * CAP;
  const float* vg = valsg + (size_t)row * CAP;
  if (t < cnt) { s_cols[t] = cg[t]; s_u[t] = vg[t]; }
  __syncthreads();
  int f = t & 127, half = t >> 7;
  float acc = 0.f;
  int k = half;
  for (; k + 6 < cnt; k += 8) {
    int   c0 = s_cols[k],     c1 = s_cols[k + 2], c2 = s_cols[k + 4], c3 = s_cols[k + 6];
    float u0 = s_u[k],        u1 = s_u[k + 2],    u2 = s_u[k + 4],    u3 = s_u[k + 6];
    float v0 = featg[(size_t)c0 * FF + f];
    float v1 = featg[(size_t)c1 * FF + f];
    float v2 = featg[(size_t)c2 * FF + f];
    float v3 = featg[(size_t)c3 * FF + f];
    acc += u0 * v0 + u1 * v1 + u2 * v2 + u3 * v3;
  }
  for (; k < cnt; k += 2)
    acc += s_u[k] * featg[(size_t)s_cols[k] * FF + f];
  s_part[t] = acc;
  __syncthreads();
  if (t < FF) {
    float prop2 = s_part[t] + s_part[t + FF];
    float ft = featg[(size_t)row * FF + t];
    float rs = rowsumg[row];
    float coe1 = 1.f / (1.f + expf(-temp[1]));
    float coe3 = 1.f / (1.f + expf(-temp[3]));
    float odd = ft - prop2;
    float even = coe3 * prop2 + odd * rs;
    float fp = coe1 * even + (1.f - coe1) * odd;
    out[(size_t)row * FF + t] = 0.2f * fp + 0.8f * h0[(size_t)row * FF + t];
  }
}

extern "C" void kernel_launch(void* const* d_in, const int* in_sizes, int n_in,
                              void* d_out, int out_size, void* d_ws, size_t ws_size,
                              hipStream_t stream) {
  const float* x    = (const float*)d_in[0];
  const float* h0   = (const float*)d_in[1];
  const float* adj  = (const float*)d_in[2];
  const float* a    = (const float*)d_in[3];
  const float* temp = (const float*)d_in[4];
  float* out = (float*)d_out;

  float* f1 = (float*)d_ws;
  float* f2 = f1 + NN;
  float* rowsum = f2 + NN;
  int*   nnz = (int*)(rowsum + NN);
  int*   cols = nnz + NN;
  float* vals = (float*)(cols + (size_t)NN * CAP);
  float* feat = vals + (size_t)NN * CAP;

  k_scores<<<NN / 4, 256, 0, stream>>>(x, a, f1, f2);
  k_build<<<NN, 256, 0, stream>>>(adj, x, f1, f2, temp, nnz, cols, vals, rowsum, feat);
  k_apply<<<NN, 256, 0, stream>>>(feat, h0, temp, nnz, cols, vals, rowsum, out);
}

// Round 5
// 84.526 us; speedup vs baseline: 1.7346x; 1.2272x over previous
//
#include <hip/hip_runtime.h>
#include <math.h>

#define NN 8192
#define FF 128
#define CAP 128

typedef float nfloat4 __attribute__((ext_vector_type(4)));

// --- per-row attention dots: f1[i] = x[i]·a[0:128], f2[i] = x[i]·a[128:256]
__global__ __launch_bounds__(256) void k_scores(const float* __restrict__ x,
                                                const float* __restrict__ a,
                                                float* __restrict__ f1,
                                                float* __restrict__ f2) {
  int gid = blockIdx.x * blockDim.x + threadIdx.x;
  int row = gid >> 6;
  int lane = gid & 63;
  if (row >= NN) return;
  const float* xr = x + (size_t)row * FF;
  float v0 = xr[lane], v1 = xr[lane + 64];
  float s1 = v0 * a[lane] + v1 * a[lane + 64];
  float s2 = v0 * a[FF + lane] + v1 * a[FF + lane + 64];
  #pragma unroll
  for (int off = 32; off > 0; off >>= 1) {
    s1 += __shfl_down(s1, off);
    s2 += __shfl_down(s2, off);
  }
  if (lane == 0) { f1[row] = s1; f2[row] = s2; }
}

// --- pure stream+compact: adj row -> nnz, cols (nothing else)
__global__ __launch_bounds__(256) void k_scan(const float* __restrict__ adj,
                                              int* __restrict__ nnzg,
                                              int* __restrict__ colsg) {
  const int row = blockIdx.x;
  const int t = threadIdx.x;
  const int lane = t & 63, w = t >> 6;
  __shared__ int s_cnt[32];

  const nfloat4* arow = (const nfloat4*)(adj + (size_t)row * NN);
  unsigned msk[8];
  int within[8];
  const unsigned long long lt = (1ull << lane) - 1ull;
  #pragma unroll
  for (int it = 0; it < 8; ++it) {
    nfloat4 v = __builtin_nontemporal_load(&arow[it * 256 + t]);
    bool c0 = v.x > 0.f, c1 = v.y > 0.f, c2 = v.z > 0.f, c3 = v.w > 0.f;
    unsigned long long b0 = __ballot(c0), b1 = __ballot(c1),
                       b2 = __ballot(c2), b3 = __ballot(c3);
    within[it] = __popcll(b0 & lt) + __popcll(b1 & lt) +
                 __popcll(b2 & lt) + __popcll(b3 & lt);
    msk[it] = (c0 ? 1u : 0u) | (c1 ? 2u : 0u) | (c2 ? 4u : 0u) | (c3 ? 8u : 0u);
    if (lane == 0)
      s_cnt[it * 4 + w] = __popcll(b0) + __popcll(b1) + __popcll(b2) + __popcll(b3);
  }
  __syncthreads();

  int base[8];
  int run = 0;
  #pragma unroll
  for (int it = 0; it < 8; ++it) {
    #pragma unroll
    for (int ww = 0; ww < 4; ++ww) {
      if (ww == w) base[it] = run;
      run += s_cnt[it * 4 + ww];
    }
  }
  if (t == 0) nnzg[row] = run < CAP ? run : CAP;

  int* cg = colsg + (size_t)row * CAP;
  #pragma unroll
  for (int it = 0; it < 8; ++it) {
    unsigned m = msk[it];
    if (m) {
      int pos = base[it] + within[it];
      int j0 = (it * 256 + t) * 4;
      if (m & 1u) { if (pos < CAP) cg[pos] = j0;     pos++; }
      if (m & 2u) { if (pos < CAP) cg[pos] = j0 + 1; pos++; }
      if (m & 4u) { if (pos < CAP) cg[pos] = j0 + 2; pos++; }
      if (m & 8u) { if (pos < CAP) cg[pos] = j0 + 3; pos++; }
    }
  }
}

// --- one wave per row: softmax -> vals/rowsum, SpMM U@x, forward lifting
__global__ __launch_bounds__(256) void k_fwd(
    const float* __restrict__ x,
    const float* __restrict__ f1g, const float* __restrict__ f2g,
    const float* __restrict__ temp,
    const int* __restrict__ nnzg, const int* __restrict__ colsg,
    float* __restrict__ valsg, float* __restrict__ rowsumg,
    float* __restrict__ featg) {
  const int wl = threadIdx.x >> 6;
  const int lane = threadIdx.x & 63;
  const int row = blockIdx.x * 4 + wl;

  __shared__ int   s_c[4][CAP];
  __shared__ float s_u[4][CAP];

  const int cnt = nnzg[row];
  const int* cg = colsg + (size_t)row * CAP;
  const int i0 = lane, i1 = lane + 64;
  int col0 = (i0 < cnt) ? cg[i0] : 0;
  int col1 = (i1 < cnt) ? cg[i1] : 0;

  const float F1 = f1g[row];
  float e0 = -INFINITY, e1 = -INFINITY;
  if (i0 < cnt) { float s = F1 + f2g[col0]; e0 = s > 0.f ? s : 0.2f * s; }
  if (i1 < cnt) { float s = F1 + f2g[col1]; e1 = s > 0.f ? s : 0.2f * s; }
  float mx = fmaxf(e0, e1);
  #pragma unroll
  for (int off = 32; off > 0; off >>= 1) mx = fmaxf(mx, __shfl_xor(mx, off));
  float p0 = (i0 < cnt) ? expf(e0 - mx) : 0.f;
  float p1 = (i1 < cnt) ? expf(e1 - mx) : 0.f;
  float sm = p0 + p1;
  #pragma unroll
  for (int off = 32; off > 0; off >>= 1) sm += __shfl_xor(sm, off);
  float inv = 1.f / sm;
  float u0 = p0 * inv, u1 = p1 * inv;
  float q = u0 * u0 + u1 * u1;
  #pragma unroll
  for (int off = 32; off > 0; off >>= 1) q += __shfl_xor(q, off);
  float rs = 0.5f * q;

  if (i0 < cnt) { s_c[wl][i0] = col0; s_u[wl][i0] = u0; }
  if (i1 < cnt) { s_c[wl][i1] = col1; s_u[wl][i1] = u1; }
  float* vg = valsg + (size_t)row * CAP;
  if (i0 < cnt) vg[i0] = u0;
  if (i1 < cnt) vg[i1] = u1;
  if (lane == 0) rowsumg[row] = rs;
  __syncthreads();

  // SpMM: lane covers features f=lane and f=lane+64; 4 entries/round, 8 loads in flight
  float acc0 = 0.f, acc1 = 0.f;
  int k = 0;
  for (; k + 3 < cnt; k += 4) {
    int   c0 = s_c[wl][k],   c1 = s_c[wl][k+1], c2 = s_c[wl][k+2], c3 = s_c[wl][k+3];
    float w0 = s_u[wl][k],   w1 = s_u[wl][k+1], w2 = s_u[wl][k+2], w3 = s_u[wl][k+3];
    float a0 = x[(size_t)c0 * FF + lane],      b0 = x[(size_t)c0 * FF + lane + 64];
    float a1 = x[(size_t)c1 * FF + lane],      b1 = x[(size_t)c1 * FF + lane + 64];
    float a2 = x[(size_t)c2 * FF + lane],      b2 = x[(size_t)c2 * FF + lane + 64];
    float a3 = x[(size_t)c3 * FF + lane],      b3 = x[(size_t)c3 * FF + lane + 64];
    acc0 += w0 * a0 + w1 * a1 + w2 * a2 + w3 * a3;
    acc1 += w0 * b0 + w1 * b1 + w2 * b2 + w3 * b3;
  }
  for (; k < cnt; ++k) {
    int c = s_c[wl][k]; float u = s_u[wl][k];
    acc0 += u * x[(size_t)c * FF + lane];
    acc1 += u * x[(size_t)c * FF + lane + 64];
  }

  const float coe2 = 1.f / (1.f + expf(-temp[2]));
  float xv0 = x[(size_t)row * FF + lane];
  float xv1 = x[(size_t)row * FF + lane + 64];
  featg[(size_t)row * FF + lane]      = acc0 - xv0 * rs + (1.f - coe2) * xv0;
  featg[(size_t)row * FF + lane + 64] = acc1 - xv1 * rs + (1.f - coe2) * xv1;
}

// --- one wave per row: SpMM U@feat, inverse lifting, output blend
__global__ __launch_bounds__(256) void k_bwd(
    const float* __restrict__ featg, const float* __restrict__ h0,
    const float* __restrict__ temp,
    const int* __restrict__ nnzg, const int* __restrict__ colsg,
    const float* __restrict__ valsg, const float* __restrict__ rowsumg,
    float* __restrict__ out) {
  const int wl = threadIdx.x >> 6;
  const int lane = threadIdx.x & 63;
  const int row = blockIdx.x * 4 + wl;

  __shared__ int   s_c[4][CAP];
  __shared__ float s_u[4][CAP];

  const int cnt = nnzg[row];
  const int* cg = colsg + (size_t)row * CAP;
  const float* vg = valsg + (size_t)row * CAP;
  const int i0 = lane, i1 = lane + 64;
  if (i0 < cnt) { s_c[wl][i0] = cg[i0]; s_u[wl][i0] = vg[i0]; }
  if (i1 < cnt) { s_c[wl][i1] = cg[i1]; s_u[wl][i1] = vg[i1]; }
  __syncthreads();

  float acc0 = 0.f, acc1 = 0.f;
  int k = 0;
  for (; k + 3 < cnt; k += 4) {
    int   c0 = s_c[wl][k],   c1 = s_c[wl][k+1], c2 = s_c[wl][k+2], c3 = s_c[wl][k+3];
    float w0 = s_u[wl][k],   w1 = s_u[wl][k+1], w2 = s_u[wl][k+2], w3 = s_u[wl][k+3];
    float a0 = featg[(size_t)c0 * FF + lane],  b0 = featg[(size_t)c0 * FF + lane + 64];
    float a1 = featg[(size_t)c1 * FF + lane],  b1 = featg[(size_t)c1 * FF + lane + 64];
    float a2 = featg[(size_t)c2 * FF + lane],  b2 = featg[(size_t)c2 * FF + lane + 64];
    float a3 = featg[(size_t)c3 * FF + lane],  b3 = featg[(size_t)c3 * FF + lane + 64];
    acc0 += w0 * a0 + w1 * a1 + w2 * a2 + w3 * a3;
    acc1 += w0 * b0 + w1 * b1 + w2 * b2 + w3 * b3;
  }
  for (; k < cnt; ++k) {
    int c = s_c[wl][k]; float u = s_u[wl][k];
    acc0 += u * featg[(size_t)c * FF + lane];
    acc1 += u * featg[(size_t)c * FF + lane + 64];
  }

  const float rs = rowsumg[row];
  const float coe1 = 1.f / (1.f + expf(-temp[1]));
  const float coe3 = 1.f / (1.f + expf(-temp[3]));
  float ft0 = featg[(size_t)row * FF + lane];
  float ft1 = featg[(size_t)row * FF + lane + 64];
  float odd0 = ft0 - acc0, odd1 = ft1 - acc1;
  float ev0 = coe3 * acc0 + odd0 * rs;
  float ev1 = coe3 * acc1 + odd1 * rs;
  float fp0 = coe1 * ev0 + (1.f - coe1) * odd0;
  float fp1 = coe1 * ev1 + (1.f - coe1) * odd1;
  out[(size_t)row * FF + lane]      = 0.2f * fp0 + 0.8f * h0[(size_t)row * FF + lane];
  out[(size_t)row * FF + lane + 64] = 0.2f * fp1 + 0.8f * h0[(size_t)row * FF + lane + 64];
}

extern "C" void kernel_launch(void* const* d_in, const int* in_sizes, int n_in,
                              void* d_out, int out_size, void* d_ws, size_t ws_size,
                              hipStream_t stream) {
  const float* x    = (const float*)d_in[0];
  const float* h0   = (const float*)d_in[1];
  const float* adj  = (const float*)d_in[2];
  const float* a    = (const float*)d_in[3];
  const float* temp = (const float*)d_in[4];
  float* out = (float*)d_out;

  float* f1 = (float*)d_ws;
  float* f2 = f1 + NN;
  float* rowsum = f2 + NN;
  int*   nnz = (int*)(rowsum + NN);
  int*   cols = nnz + NN;
  float* vals = (float*)(cols + (size_t)NN * CAP);
  float* feat = vals + (size_t)NN * CAP;

  k_scores<<<NN / 4, 256, 0, stream>>>(x, a, f1, f2);
  k_scan<<<NN, 256, 0, stream>>>(adj, nnz, cols);
  k_fwd<<<NN / 4, 256, 0, stream>>>(x, f1, f2, temp, nnz, cols, vals, rowsum, feat);
  k_bwd<<<NN / 4, 256, 0, stream>>>(feat, h0, temp, nnz, cols, vals, rowsum, out);
}